// Round 11
// baseline (291.907 us; speedup 1.0000x reference)
//
#include <hip/hip_runtime.h>
#include <hip/hip_bf16.h>
#include <stdint.h>

#define M_TOK 8192
#define N_OUT 4096
#define K_IN  4096

#define BM 256
#define BN 256
#define BKB 128            // K-tile depth in BYTES (= 128 i8 elements)
#define NT (K_IN / BKB)    // 32 K-tiles

typedef __attribute__((ext_vector_type(4))) int   i32x4;

#define AS1 __attribute__((address_space(1)))
#define AS3 __attribute__((address_space(3)))
#define GLOAD_LDS16(g, l) \
  __builtin_amdgcn_global_load_lds((AS1 void*)(g), (AS3 void*)(l), 16, 0, 0)

#define BAR()      __builtin_amdgcn_s_barrier()
#define VMCNT4()   asm volatile("s_waitcnt vmcnt(4)" ::: "memory")
#define VMCNT8()   asm volatile("s_waitcnt vmcnt(8)" ::: "memory")
#define PRIO(p)    __builtin_amdgcn_s_setprio(p)
#define MFMAI8(a, b, c) __builtin_amdgcn_mfma_i32_16x16x64_i8((a), (b), (c), 0, 0, 0)

// ---------------- prep: x fp32 -> i8 with per-row scale (RNE) ----------------
__global__ __launch_bounds__(256) void quant_x_i8(const float4* __restrict__ x,
                                                  int4* __restrict__ o,
                                                  float* __restrict__ scales) {
  const int row = blockIdx.x;
  const int t   = threadIdx.x;
  const float4* xr = x + (size_t)row * (K_IN / 4);
  float4 v[4];
  #pragma unroll
  for (int i = 0; i < 4; ++i) v[i] = xr[t * 4 + i];
  float m = 0.f;
  #pragma unroll
  for (int i = 0; i < 4; ++i)
    m = fmaxf(m, fmaxf(fmaxf(fabsf(v[i].x), fabsf(v[i].y)),
                       fmaxf(fabsf(v[i].z), fabsf(v[i].w))));
  #pragma unroll
  for (int off = 32; off; off >>= 1) m = fmaxf(m, __shfl_down(m, off));
  __shared__ float sm[4];
  if ((t & 63) == 0) sm[t >> 6] = m;
  __syncthreads();
  m = fmaxf(fmaxf(sm[0], sm[1]), fmaxf(sm[2], sm[3]));
  const float inv = m > 0.f ? 127.f / m : 0.f;
  if (t == 0) scales[row] = m > 0.f ? m / 127.f : 1.f;
  int q[4];
  #pragma unroll
  for (int i = 0; i < 4; ++i) {
    const int a0 = (int)rintf(v[i].x * inv);
    const int a1 = (int)rintf(v[i].y * inv);
    const int a2 = (int)rintf(v[i].z * inv);
    const int a3 = (int)rintf(v[i].w * inv);
    q[i] = (a0 & 255) | ((a1 & 255) << 8) | ((a2 & 255) << 16) | (a3 << 24);
  }
  o[(size_t)row * (K_IN / 16) + t] = make_int4(q[0], q[1], q[2], q[3]);
}

// ---------------- prep: W fp32 -> sign in i8 {-1, 0, +1} ----------------
__global__ __launch_bounds__(256) void sgn_w_i8(const float4* __restrict__ w,
                                                int4* __restrict__ o, int n16) {
  int i = blockIdx.x * blockDim.x + threadIdx.x;
  int stride = gridDim.x * blockDim.x;
  for (; i < n16; i += stride) {
    int q[4];
    #pragma unroll
    for (int j = 0; j < 4; ++j) {
      float4 v = w[i * 4 + j];
      const int a0 = v.x > 0.f ? 1 : (v.x < 0.f ? -1 : 0);
      const int a1 = v.y > 0.f ? 1 : (v.y < 0.f ? -1 : 0);
      const int a2 = v.z > 0.f ? 1 : (v.z < 0.f ? -1 : 0);
      const int a3 = v.w > 0.f ? 1 : (v.w < 0.f ? -1 : 0);
      q[j] = (a0 & 255) | ((a1 & 255) << 8) | ((a2 & 255) << 16) | (a3 << 24);
    }
    o[i] = make_int4(q[0], q[1], q[2], q[3]);
  }
}

// ======== 256x256 i8 GEMM, A via LDS / B direct from global (L2) ========
// C[t][o] = (x_q[t][:] . w_q[o][:]) * scale[t].  i32 accumulate (exact).
// Round-10 post-mortem: staging t+2 into the SAME-parity buffer mid-tile raced
// other waves' k1 reads (absmax 338). Fixed staging discipline:
//   even tile t (reads Le): stage t+1 -> Lo at TOP of body. Lo's last reads
//   were in odd tile t-1; every ds_read's data is consumed by an MFMA before
//   that tile's end barrier => lgkm-retired; barrier globalizes. Writes land
//   strictly after. Symmetric for odd tiles.
// Issue order per tile: {stage 4 | b1 4 | b-next 4} -> tile-end vmcnt(8)
// retires the stage (8 newer ops), keeps b-next in flight. Never vmcnt(0).
// B-frags load straight from global: per XCD only 2 B-panels (2 MB) are live
// (bn%8 == xcd for default dispatch), so B reads are L2-served; pattern reads
// full 64-B lines (4 lk-lanes x 16 B per row). LDS port/tile drops to
// A-reads 128K + A-stage 32K ~= 1900 cyc < 2611-cyc matrix floor.
__global__ __launch_bounds__(512, 2) void bin_gemm_i8(const char* __restrict__ A,
                                                      const char* __restrict__ B,
                                                      const float* __restrict__ scales,
                                                      float* __restrict__ C) {
  __shared__ char lds[65536];   // 2 buf x A 32KB

  const int tid  = threadIdx.x;
  const int w    = tid >> 6;
  const int lane = tid & 63;
  const int lr   = lane & 15;    // fragment row/col
  const int lk   = lane >> 4;    // k-group 0..3 (16 bytes each)
  const int wr   = w >> 2;       // wave row 0..1  (128 rows each)
  const int wc   = w & 3;        // wave col 0..3  (64 cols each)

  const int bm = blockIdx.x >> 4;     // M/256 = 32
  const int bn = blockIdx.x & 15;     // N/256 = 16

  const char* Ag = A + (size_t)bm * BM * K_IN;
  const char* Bg = B + (size_t)bn * BN * K_IN;

  // A staging: linear LDS dest + inverse-swizzled global source (rule #21).
  const int c0 = w * 128 + lane;
  const int c1 = c0 + 64;
  const int r0 = c0 >> 3, r1 = c1 >> 3;
  const size_t g0 = (size_t)r0 * K_IN + (size_t)(((c0 ^ r0) & 7) << 4);
  const size_t g1 = (size_t)r1 * K_IN + (size_t)(((c1 ^ r1) & 7) << 4);
  const int ldsw = w * 2048;

  auto stageA = [&](int half, int tt) {
    const char* g = Ag + (size_t)half * (128 * K_IN) + (size_t)tt * BKB;
    char* l = &lds[((tt & 1) << 15) + (half << 14) + ldsw];
    GLOAD_LDS16(g + g0, l);
    GLOAD_LDS16(g + g1, l + 1024);
  };

  // A fragment reads (swizzled): (row)*128 + ((ks*64 + lk*16) ^ ((row&7)<<4))
  const int swz   = (lr & 7) << 4;
  const int a_row = (wr * 128 + lr) * 128;
  const int k0 = (lk * 16) ^ swz;
  const int k1 = (64 + lk * 16) ^ swz;

  // B fragment global base: row (wc*64 + n*16 + lr), bytes t*128 + ks*64 + lk*16
  const char* Bw = Bg + (size_t)(wc * 64 + lr) * K_IN + lk * 16;
  auto loadB = [&](i32x4* dst, int tt, int ks) {
    #pragma unroll
    for (int n = 0; n < 4; ++n)
      dst[n] = *(const i32x4*)(Bw + (size_t)n * 16 * K_IN
                                  + (size_t)tt * BKB + ks * 64);
  };

  i32x4 acc[8][4];
  #pragma unroll
  for (int m = 0; m < 8; ++m)
    #pragma unroll
    for (int n = 0; n < 4; ++n) { i32x4 z = {0, 0, 0, 0}; acc[m][n] = z; }

  i32x4 aH[8], b1[4], bE0[4], bO0[4];

  // prologue: stage A tile 0 -> Le; load B(0,ks0); drain stage(0) only.
  stageA(0, 0); stageA(1, 0);          // 4 vmem
  loadB(bE0, 0, 0);                    // 4 vmem (newer)
  VMCNT4();                            // stage(0) retired; bE0 in flight
  BAR();

  for (int t = 0; t < NT; t += 2) {
    const char* Le = &lds[0];       // even-tile buffer
    const char* Lo = &lds[32768];   // odd-tile buffer

    // ================= even tile t (reads Le) =================
    stageA(0, t + 1); stageA(1, t + 1);            // -> Lo (safe: see header)
    loadB(b1, t, 1);                               // B(t, ks1)
    #pragma unroll
    for (int m = 0; m < 8; ++m) aH[m] = *(const i32x4*)(Le + a_row + m * 2048 + k0);
    PRIO(1);
    #pragma unroll
    for (int q = 0; q < 4; ++q)
      #pragma unroll
      for (int m = 0; m < 8; ++m)
        acc[m][q] = MFMAI8(aH[m], bE0[q], acc[m][q]);
    PRIO(0);
    loadB(bO0, t + 1, 0);                          // B(t+1, ks0)
    #pragma unroll
    for (int m = 0; m < 8; ++m) aH[m] = *(const i32x4*)(Le + a_row + m * 2048 + k1);
    PRIO(1);
    #pragma unroll
    for (int q = 0; q < 4; ++q)
      #pragma unroll
      for (int m = 0; m < 8; ++m)
        acc[m][q] = MFMAI8(aH[m], b1[q], acc[m][q]);
    PRIO(0);
    VMCNT8();       // stage(t+1) retired (8 newer: b1 + bO0); bO0 keeps flying
    BAR();

    // ================= odd tile t+1 (reads Lo) =================
    if (t + 2 < NT) { stageA(0, t + 2); stageA(1, t + 2); }   // -> Le (safe)
    loadB(b1, t + 1, 1);                           // B(t+1, ks1)
    #pragma unroll
    for (int m = 0; m < 8; ++m) aH[m] = *(const i32x4*)(Lo + a_row + m * 2048 + k0);
    PRIO(1);
    #pragma unroll
    for (int q = 0; q < 4; ++q)
      #pragma unroll
      for (int m = 0; m < 8; ++m)
        acc[m][q] = MFMAI8(aH[m], bO0[q], acc[m][q]);
    PRIO(0);
    if (t + 2 < NT) loadB(bE0, t + 2, 0);          // B(t+2, ks0)
    #pragma unroll
    for (int m = 0; m < 8; ++m) aH[m] = *(const i32x4*)(Lo + a_row + m * 2048 + k1);
    PRIO(1);
    #pragma unroll
    for (int q = 0; q < 4; ++q)
      #pragma unroll
      for (int m = 0; m < 8; ++m)
        acc[m][q] = MFMAI8(aH[m], b1[q], acc[m][q]);
    PRIO(0);
    VMCNT8();       // stage(t+2) retired before next even tile reads Le
    BAR();
  }

  // epilogue: C/D layout col=lane&15, row=(lane>>4)*4+reg; y = acc * scale[row]
  const int grow0 = bm * BM + wr * 128;
  float scl[8][4];
  #pragma unroll
  for (int m = 0; m < 8; ++m)
    #pragma unroll
    for (int j = 0; j < 4; ++j)
      scl[m][j] = scales[grow0 + m * 16 + lk * 4 + j];

  float* Cp = C + (size_t)grow0 * N_OUT + bn * BN + wc * 64;
  #pragma unroll
  for (int m = 0; m < 8; ++m)
    #pragma unroll
    for (int n = 0; n < 4; ++n)
      #pragma unroll
      for (int j = 0; j < 4; ++j)
        Cp[(size_t)(m * 16 + lk * 4 + j) * N_OUT + n * 16 + lr] =
            (float)acc[m][n][j] * scl[m][j];
}

// ---------------- fallback (ws too small): fp32 LDS-tiled, correct but slow --
__global__ __launch_bounds__(256) void fb_gemm(const float* __restrict__ x,
                                               const float* __restrict__ W,
                                               float* __restrict__ y) {
  __shared__ float xs[32][33];
  __shared__ float ws[32][33];
  const int bx = blockIdx.x;
  const int by = blockIdx.y;
  const int tx = threadIdx.x & 31;
  const int ty = threadIdx.x >> 5;
  float acc[4] = {0.f, 0.f, 0.f, 0.f};
  for (int k0 = 0; k0 < K_IN; k0 += 32) {
    #pragma unroll
    for (int i = 0; i < 4; ++i) {
      int r = ty + i * 8;
      xs[r][tx] = x[(size_t)(by * 32 + r) * K_IN + k0 + tx];
      float wv = W[(size_t)(bx * 32 + r) * K_IN + k0 + tx];
      ws[r][tx] = wv > 0.f ? 1.f : (wv < 0.f ? -1.f : 0.f);
    }
    __syncthreads();
    #pragma unroll
    for (int i = 0; i < 4; ++i) {
      int r = ty + i * 8;
      float s = acc[i];
      #pragma unroll
      for (int k = 0; k < 32; ++k) s += xs[r][k] * ws[tx][k];
      acc[i] = s;
    }
    __syncthreads();
  }
  #pragma unroll
  for (int i = 0; i < 4; ++i)
    y[(size_t)(by * 32 + ty + i * 8) * N_OUT + bx * 32 + tx] = acc[i];
}

extern "C" void kernel_launch(void* const* d_in, const int* in_sizes, int n_in,
                              void* d_out, int out_size, void* d_ws, size_t ws_size,
                              hipStream_t stream) {
  const float* x = (const float*)d_in[0];   // [8192, 4096]
  const float* W = (const float*)d_in[1];   // [4096, 4096]
  float* y = (float*)d_out;                 // [8192, 4096]

  const size_t need = (size_t)M_TOK * K_IN + (size_t)N_OUT * K_IN
                    + (size_t)M_TOK * sizeof(float);
  if (ws_size >= need) {
    char*  xq = (char*)d_ws;
    char*  wq = xq + (size_t)M_TOK * K_IN;
    float* sc = (float*)(wq + (size_t)N_OUT * K_IN);
    quant_x_i8<<<M_TOK, 256, 0, stream>>>((const float4*)x, (int4*)xq, sc);
    sgn_w_i8<<<2048, 256, 0, stream>>>((const float4*)W, (int4*)wq,
                                       N_OUT * K_IN / 16);
    bin_gemm_i8<<<(M_TOK / BM) * (N_OUT / BN), 512, 0, stream>>>(xq, wq, sc, y);
  } else {
    dim3 g(N_OUT / 32, M_TOK / 32);
    fb_gemm<<<g, 256, 0, stream>>>(x, W, y);
  }
}

// Round 12
// 291.079 us; speedup vs baseline: 1.0028x; 1.0028x over previous
//
#include <hip/hip_runtime.h>
#include <hip/hip_bf16.h>
#include <stdint.h>

#define M_TOK 8192
#define N_OUT 4096
#define K_IN  4096

#define BM 256
#define BN 256
#define BKB 128            // K-tile depth in BYTES (= 128 i8 elements)
#define NT (K_IN / BKB)    // 32 K-tiles

typedef __attribute__((ext_vector_type(4))) int   i32x4;

#define AS1 __attribute__((address_space(1)))
#define AS3 __attribute__((address_space(3)))
#define GLOAD_LDS16(g, l) \
  __builtin_amdgcn_global_load_lds((AS1 void*)(g), (AS3 void*)(l), 16, 0, 0)

#define BAR()      __builtin_amdgcn_s_barrier()
#define VMCNT4()   asm volatile("s_waitcnt vmcnt(4)" ::: "memory")
#define VMCNT8()   asm volatile("s_waitcnt vmcnt(8)" ::: "memory")
#define PRIO(p)    __builtin_amdgcn_s_setprio(p)
#define MFMAI8(a, b, c) __builtin_amdgcn_mfma_i32_16x16x64_i8((a), (b), (c), 0, 0, 0)

// ---------------- prep: x fp32 -> i8 with per-row scale (RNE) ----------------
__global__ __launch_bounds__(256) void quant_x_i8(const float4* __restrict__ x,
                                                  int4* __restrict__ o,
                                                  float* __restrict__ scales) {
  const int row = blockIdx.x;
  const int t   = threadIdx.x;
  const float4* xr = x + (size_t)row * (K_IN / 4);
  float4 v[4];
  #pragma unroll
  for (int i = 0; i < 4; ++i) v[i] = xr[t * 4 + i];
  float m = 0.f;
  #pragma unroll
  for (int i = 0; i < 4; ++i)
    m = fmaxf(m, fmaxf(fmaxf(fabsf(v[i].x), fabsf(v[i].y)),
                       fmaxf(fabsf(v[i].z), fabsf(v[i].w))));
  #pragma unroll
  for (int off = 32; off; off >>= 1) m = fmaxf(m, __shfl_down(m, off));
  __shared__ float sm[4];
  if ((t & 63) == 0) sm[t >> 6] = m;
  __syncthreads();
  m = fmaxf(fmaxf(sm[0], sm[1]), fmaxf(sm[2], sm[3]));
  const float inv = m > 0.f ? 127.f / m : 0.f;
  if (t == 0) scales[row] = m > 0.f ? m / 127.f : 1.f;
  int q[4];
  #pragma unroll
  for (int i = 0; i < 4; ++i) {
    const int a0 = (int)rintf(v[i].x * inv);
    const int a1 = (int)rintf(v[i].y * inv);
    const int a2 = (int)rintf(v[i].z * inv);
    const int a3 = (int)rintf(v[i].w * inv);
    q[i] = (a0 & 255) | ((a1 & 255) << 8) | ((a2 & 255) << 16) | (a3 << 24);
  }
  o[(size_t)row * (K_IN / 16) + t] = make_int4(q[0], q[1], q[2], q[3]);
}

// ---------------- prep: W fp32 -> sign in i8 {-1, 0, +1} ----------------
__global__ __launch_bounds__(256) void sgn_w_i8(const float4* __restrict__ w,
                                                int4* __restrict__ o, int n16) {
  int i = blockIdx.x * blockDim.x + threadIdx.x;
  int stride = gridDim.x * blockDim.x;
  for (; i < n16; i += stride) {
    int q[4];
    #pragma unroll
    for (int j = 0; j < 4; ++j) {
      float4 v = w[i * 4 + j];
      const int a0 = v.x > 0.f ? 1 : (v.x < 0.f ? -1 : 0);
      const int a1 = v.y > 0.f ? 1 : (v.y < 0.f ? -1 : 0);
      const int a2 = v.z > 0.f ? 1 : (v.z < 0.f ? -1 : 0);
      const int a3 = v.w > 0.f ? 1 : (v.w < 0.f ? -1 : 0);
      q[j] = (a0 & 255) | ((a1 & 255) << 8) | ((a2 & 255) << 16) | (a3 << 24);
    }
    o[i] = make_int4(q[0], q[1], q[2], q[3]);
  }
}

// ======== 256x256 i8 GEMM, A via LDS / B direct from global (L2) ========
// Round-11 post-mortem: the 64 KB LDS silently DOUBLED occupancy to 2
// blocks/CU -> all 512 blocks co-resident -> simultaneous C-epilogue burst
// thrashed L2 (WRITE_SIZE 165->410 MB) and confounded the B-direct test.
// This round: IDENTICAL kernel but LDS padded to 96 KiB to force 1 block/CU
// (same 8 waves/CU as rounds <=9) -> clean test of the LDS-port theory:
// port traffic/CU-tile 192->128 KB with B-frags served from L2 (2 panels =
// 2 MB per XCD; full 64-B lines per 4-lane group).
// Staging discipline (race-free, validated r11): even tile t reads Le,
// stages t+1 -> Lo at TOP (Lo's reads all lgkm-retired before t-1's end
// barrier); odd symmetric. Tile-end vmcnt(8) retires the stage, keeps the
// 4 b-next loads in flight. Never vmcnt(0) in the loop.
__global__ __launch_bounds__(512, 2) void bin_gemm_i8(const char* __restrict__ A,
                                                      const char* __restrict__ B,
                                                      const float* __restrict__ scales,
                                                      float* __restrict__ C) {
  __shared__ char lds[98304];   // 64 KB used (2 buf x A 32KB) + 32 KB pad:
                                // 2x98304 > 160 KiB => exactly 1 block/CU.

  const int tid  = threadIdx.x;
  const int w    = tid >> 6;
  const int lane = tid & 63;
  const int lr   = lane & 15;    // fragment row/col
  const int lk   = lane >> 4;    // k-group 0..3 (16 bytes each)
  const int wr   = w >> 2;       // wave row 0..1  (128 rows each)
  const int wc   = w & 3;        // wave col 0..3  (64 cols each)

  const int bm = blockIdx.x >> 4;     // M/256 = 32
  const int bn = blockIdx.x & 15;     // N/256 = 16

  const char* Ag = A + (size_t)bm * BM * K_IN;
  const char* Bg = B + (size_t)bn * BN * K_IN;

  // A staging: linear LDS dest + inverse-swizzled global source (rule #21).
  const int c0 = w * 128 + lane;
  const int c1 = c0 + 64;
  const int r0 = c0 >> 3, r1 = c1 >> 3;
  const size_t g0 = (size_t)r0 * K_IN + (size_t)(((c0 ^ r0) & 7) << 4);
  const size_t g1 = (size_t)r1 * K_IN + (size_t)(((c1 ^ r1) & 7) << 4);
  const int ldsw = w * 2048;

  auto stageA = [&](int half, int tt) {
    const char* g = Ag + (size_t)half * (128 * K_IN) + (size_t)tt * BKB;
    char* l = &lds[((tt & 1) << 15) + (half << 14) + ldsw];
    GLOAD_LDS16(g + g0, l);
    GLOAD_LDS16(g + g1, l + 1024);
  };

  // A fragment reads (swizzled): (row)*128 + ((ks*64 + lk*16) ^ ((row&7)<<4))
  const int swz   = (lr & 7) << 4;
  const int a_row = (wr * 128 + lr) * 128;
  const int k0 = (lk * 16) ^ swz;
  const int k1 = (64 + lk * 16) ^ swz;

  // B fragment global base: row (wc*64 + n*16 + lr), bytes t*128 + ks*64 + lk*16
  const char* Bw = Bg + (size_t)(wc * 64 + lr) * K_IN + lk * 16;
  auto loadB = [&](i32x4* dst, int tt, int ks) {
    #pragma unroll
    for (int n = 0; n < 4; ++n)
      dst[n] = *(const i32x4*)(Bw + (size_t)n * 16 * K_IN
                                  + (size_t)tt * BKB + ks * 64);
  };

  i32x4 acc[8][4];
  #pragma unroll
  for (int m = 0; m < 8; ++m)
    #pragma unroll
    for (int n = 0; n < 4; ++n) { i32x4 z = {0, 0, 0, 0}; acc[m][n] = z; }

  i32x4 aH[8], b1[4], bE0[4], bO0[4];

  // prologue: stage A tile 0 -> Le; load B(0,ks0); drain stage(0) only.
  stageA(0, 0); stageA(1, 0);          // 4 vmem
  loadB(bE0, 0, 0);                    // 4 vmem (newer)
  VMCNT4();                            // stage(0) retired; bE0 in flight
  BAR();

  for (int t = 0; t < NT; t += 2) {
    const char* Le = &lds[0];       // even-tile buffer
    const char* Lo = &lds[32768];   // odd-tile buffer

    // ================= even tile t (reads Le) =================
    stageA(0, t + 1); stageA(1, t + 1);            // -> Lo (safe: see header)
    loadB(b1, t, 1);                               // B(t, ks1)
    #pragma unroll
    for (int m = 0; m < 8; ++m) aH[m] = *(const i32x4*)(Le + a_row + m * 2048 + k0);
    PRIO(1);
    #pragma unroll
    for (int q = 0; q < 4; ++q)
      #pragma unroll
      for (int m = 0; m < 8; ++m)
        acc[m][q] = MFMAI8(aH[m], bE0[q], acc[m][q]);
    PRIO(0);
    loadB(bO0, t + 1, 0);                          // B(t+1, ks0)
    #pragma unroll
    for (int m = 0; m < 8; ++m) aH[m] = *(const i32x4*)(Le + a_row + m * 2048 + k1);
    PRIO(1);
    #pragma unroll
    for (int q = 0; q < 4; ++q)
      #pragma unroll
      for (int m = 0; m < 8; ++m)
        acc[m][q] = MFMAI8(aH[m], b1[q], acc[m][q]);
    PRIO(0);
    VMCNT8();       // stage(t+1) retired (8 newer: b1 + bO0); bO0 keeps flying
    BAR();

    // ================= odd tile t+1 (reads Lo) =================
    if (t + 2 < NT) { stageA(0, t + 2); stageA(1, t + 2); }   // -> Le (safe)
    loadB(b1, t + 1, 1);                           // B(t+1, ks1)
    #pragma unroll
    for (int m = 0; m < 8; ++m) aH[m] = *(const i32x4*)(Lo + a_row + m * 2048 + k0);
    PRIO(1);
    #pragma unroll
    for (int q = 0; q < 4; ++q)
      #pragma unroll
      for (int m = 0; m < 8; ++m)
        acc[m][q] = MFMAI8(aH[m], bO0[q], acc[m][q]);
    PRIO(0);
    if (t + 2 < NT) loadB(bE0, t + 2, 0);          // B(t+2, ks0)
    #pragma unroll
    for (int m = 0; m < 8; ++m) aH[m] = *(const i32x4*)(Lo + a_row + m * 2048 + k1);
    PRIO(1);
    #pragma unroll
    for (int q = 0; q < 4; ++q)
      #pragma unroll
      for (int m = 0; m < 8; ++m)
        acc[m][q] = MFMAI8(aH[m], b1[q], acc[m][q]);
    PRIO(0);
    VMCNT8();       // stage(t+2) retired before next even tile reads Le
    BAR();
  }

  // epilogue: C/D layout col=lane&15, row=(lane>>4)*4+reg; y = acc * scale[row]
  const int grow0 = bm * BM + wr * 128;
  float scl[8][4];
  #pragma unroll
  for (int m = 0; m < 8; ++m)
    #pragma unroll
    for (int j = 0; j < 4; ++j)
      scl[m][j] = scales[grow0 + m * 16 + lk * 4 + j];

  float* Cp = C + (size_t)grow0 * N_OUT + bn * BN + wc * 64;
  #pragma unroll
  for (int m = 0; m < 8; ++m)
    #pragma unroll
    for (int n = 0; n < 4; ++n)
      #pragma unroll
      for (int j = 0; j < 4; ++j)
        Cp[(size_t)(m * 16 + lk * 4 + j) * N_OUT + n * 16 + lr] =
            (float)acc[m][n][j] * scl[m][j];
}

// ---------------- fallback (ws too small): fp32 LDS-tiled, correct but slow --
__global__ __launch_bounds__(256) void fb_gemm(const float* __restrict__ x,
                                               const float* __restrict__ W,
                                               float* __restrict__ y) {
  __shared__ float xs[32][33];
  __shared__ float ws[32][33];
  const int bx = blockIdx.x;
  const int by = blockIdx.y;
  const int tx = threadIdx.x & 31;
  const int ty = threadIdx.x >> 5;
  float acc[4] = {0.f, 0.f, 0.f, 0.f};
  for (int k0 = 0; k0 < K_IN; k0 += 32) {
    #pragma unroll
    for (int i = 0; i < 4; ++i) {
      int r = ty + i * 8;
      xs[r][tx] = x[(size_t)(by * 32 + r) * K_IN + k0 + tx];
      float wv = W[(size_t)(bx * 32 + r) * K_IN + k0 + tx];
      ws[r][tx] = wv > 0.f ? 1.f : (wv < 0.f ? -1.f : 0.f);
    }
    __syncthreads();
    #pragma unroll
    for (int i = 0; i < 4; ++i) {
      int r = ty + i * 8;
      float s = acc[i];
      #pragma unroll
      for (int k = 0; k < 32; ++k) s += xs[r][k] * ws[tx][k];
      acc[i] = s;
    }
    __syncthreads();
  }
  #pragma unroll
  for (int i = 0; i < 4; ++i)
    y[(size_t)(by * 32 + ty + i * 8) * N_OUT + bx * 32 + tx] = acc[i];
}

extern "C" void kernel_launch(void* const* d_in, const int* in_sizes, int n_in,
                              void* d_out, int out_size, void* d_ws, size_t ws_size,
                              hipStream_t stream) {
  const float* x = (const float*)d_in[0];   // [8192, 4096]
  const float* W = (const float*)d_in[1];   // [4096, 4096]
  float* y = (float*)d_out;                 // [8192, 4096]

  const size_t need = (size_t)M_TOK * K_IN + (size_t)N_OUT * K_IN
                    + (size_t)M_TOK * sizeof(float);
  if (ws_size >= need) {
    char*  xq = (char*)d_ws;
    char*  wq = xq + (size_t)M_TOK * K_IN;
    float* sc = (float*)(wq + (size_t)N_OUT * K_IN);
    quant_x_i8<<<M_TOK, 256, 0, stream>>>((const float4*)x, (int4*)xq, sc);
    sgn_w_i8<<<2048, 256, 0, stream>>>((const float4*)W, (int4*)wq,
                                       N_OUT * K_IN / 16);
    bin_gemm_i8<<<(M_TOK / BM) * (N_OUT / BN), 512, 0, stream>>>(xq, wq, sc, y);
  } else {
    dim3 g(N_OUT / 32, M_TOK / 32);
    fb_gemm<<<g, 256, 0, stream>>>(x, W, y);
  }
}

// Round 13
// 189.248 us; speedup vs baseline: 1.5425x; 1.5381x over previous
//
#include <hip/hip_runtime.h>
#include <hip/hip_bf16.h>
#include <stdint.h>

#define M_TOK 8192
#define N_OUT 4096
#define K_IN  4096

#define BM 256
#define BN 256
#define BKB 128            // K-tile depth in BYTES (= 128 i8 elements)
#define NT (K_IN / BKB)    // 32 K-tiles

typedef __attribute__((ext_vector_type(4)))  int i32x4;
typedef __attribute__((ext_vector_type(16))) int i32x16;

#define AS1 __attribute__((address_space(1)))
#define AS3 __attribute__((address_space(3)))
#define GLOAD_LDS16(g, l) \
  __builtin_amdgcn_global_load_lds((AS1 void*)(g), (AS3 void*)(l), 16, 0, 0)

#define BAR()     __builtin_amdgcn_s_barrier()
#define WAITALL() asm volatile("s_waitcnt vmcnt(0) lgkmcnt(0)" ::: "memory")
#define VMCNT8()  asm volatile("s_waitcnt vmcnt(8)" ::: "memory")
#define PRIO(p)   __builtin_amdgcn_s_setprio(p)
#define MFMA32I8(a, b, c) __builtin_amdgcn_mfma_i32_32x32x32_i8((a), (b), (c), 0, 0, 0)

// ---------------- prep: x fp32 -> i8 with per-row scale (RNE) ----------------
__global__ __launch_bounds__(256) void quant_x_i8(const float4* __restrict__ x,
                                                  int4* __restrict__ o,
                                                  float* __restrict__ scales) {
  const int row = blockIdx.x;
  const int t   = threadIdx.x;
  const float4* xr = x + (size_t)row * (K_IN / 4);
  float4 v[4];
  #pragma unroll
  for (int i = 0; i < 4; ++i) v[i] = xr[t * 4 + i];
  float m = 0.f;
  #pragma unroll
  for (int i = 0; i < 4; ++i)
    m = fmaxf(m, fmaxf(fmaxf(fabsf(v[i].x), fabsf(v[i].y)),
                       fmaxf(fabsf(v[i].z), fabsf(v[i].w))));
  #pragma unroll
  for (int off = 32; off; off >>= 1) m = fmaxf(m, __shfl_down(m, off));
  __shared__ float sm[4];
  if ((t & 63) == 0) sm[t >> 6] = m;
  __syncthreads();
  m = fmaxf(fmaxf(sm[0], sm[1]), fmaxf(sm[2], sm[3]));
  const float inv = m > 0.f ? 127.f / m : 0.f;
  if (t == 0) scales[row] = m > 0.f ? m / 127.f : 1.f;
  int q[4];
  #pragma unroll
  for (int i = 0; i < 4; ++i) {
    const int a0 = (int)rintf(v[i].x * inv);
    const int a1 = (int)rintf(v[i].y * inv);
    const int a2 = (int)rintf(v[i].z * inv);
    const int a3 = (int)rintf(v[i].w * inv);
    q[i] = (a0 & 255) | ((a1 & 255) << 8) | ((a2 & 255) << 16) | (a3 << 24);
  }
  o[(size_t)row * (K_IN / 16) + t] = make_int4(q[0], q[1], q[2], q[3]);
}

// ---------------- prep: W fp32 -> sign in i8 {-1, 0, +1} ----------------
__global__ __launch_bounds__(256) void sgn_w_i8(const float4* __restrict__ w,
                                                int4* __restrict__ o, int n16) {
  int i = blockIdx.x * blockDim.x + threadIdx.x;
  int stride = gridDim.x * blockDim.x;
  for (; i < n16; i += stride) {
    int q[4];
    #pragma unroll
    for (int j = 0; j < 4; ++j) {
      float4 v = w[i * 4 + j];
      const int a0 = v.x > 0.f ? 1 : (v.x < 0.f ? -1 : 0);
      const int a1 = v.y > 0.f ? 1 : (v.y < 0.f ? -1 : 0);
      const int a2 = v.z > 0.f ? 1 : (v.z < 0.f ? -1 : 0);
      const int a3 = v.w > 0.f ? 1 : (v.w < 0.f ? -1 : 0);
      q[j] = (a0 & 255) | ((a1 & 255) << 8) | ((a2 & 255) << 16) | (a3 << 24);
    }
    o[i] = make_int4(q[0], q[1], q[2], q[3]);
  }
}

// ======== 256x256 i8 GEMM, 32x32x32 MFMA, ONE barrier per K-tile ========
// C[t][o] = (x_q[t][:] . w_q[o][:]) * scale[t].  i32 accumulate (exact).
// Base = round-6 structure (141.6 us best known): 8 waves (2Mx4N), per-wave
// 128x64 out, 128 KiB LDS dbuf, R1 {24 reads + half the MFMAs} / WAITALL+BAR /
// R2 {stage t+2 + other half}.  This round: mfma_i32_32x32x32_i8 -> 4x fewer
// MFMA instructions (issue-slot pressure hypothesis), ideal 2611->2338 cyc.
// Swizzle upgraded to row-bit-complete: f(row) = (row&7) ^ ((row>>3)&3).
// Frag slot = (2ks+hi) ^ f(l5): every consecutive 8-lane group covers all 8
// 16B slots -> conflict-free (fixes r3's 4-way row alias). Staging source
// uses the same involution (rule #21): chunk c, row r=c>>3, src slot =
// (c&7) ^ (r&7) ^ ((r>>3)&3).
// B-direct abandoned (r12): B-loads share in-order vmcnt with A-staging ->
// any B wait drains fresh HBM staging. LDS B rides lgkmcnt, decoupled.
__global__ __launch_bounds__(512, 2) void bin_gemm_i8(const char* __restrict__ A,
                                                      const char* __restrict__ B,
                                                      const float* __restrict__ scales,
                                                      float* __restrict__ C) {
  __shared__ char lds[131072];   // 2 buf x (A 32KB + B 32KB)

  const int tid  = threadIdx.x;
  const int w    = tid >> 6;
  const int lane = tid & 63;
  const int l5   = lane & 31;    // row/col within 32
  const int hi   = lane >> 5;    // k-half selector (16 B each)
  const int wr   = w >> 2;       // wave row 0..1  (128 rows each)
  const int wc   = w & 3;        // wave col 0..3  (64 cols each)

  const int bm = blockIdx.x >> 4;     // M/256 = 32
  const int bn = blockIdx.x & 15;     // N/256 = 16

  const char* Ag = A + (size_t)bm * BM * K_IN;
  const char* Bg = B + (size_t)bn * BN * K_IN;

  // staging: linear LDS dest + inverse-swizzled global source.
  // chunk c (16B) of a 128-row half: row r=c>>3, src slot (c^r)&7 ^ ((r>>3)&3)
  const int c0 = w * 128 + lane;
  const int c1 = c0 + 64;
  const int r0 = c0 >> 3, r1 = c1 >> 3;
  const size_t g0 = (size_t)r0 * K_IN
                  + (size_t)((((c0 ^ r0) & 7) ^ ((r0 >> 3) & 3)) << 4);
  const size_t g1 = (size_t)r1 * K_IN
                  + (size_t)((((c1 ^ r1) & 7) ^ ((r1 >> 3) & 3)) << 4);
  const int ldsw = w * 2048;

  auto stage = [&](int mat, int half, int tt) {
    const char* g = (mat ? Bg : Ag) + (size_t)half * (128 * K_IN)
                                    + (size_t)tt * BKB;
    char* l = &lds[((tt & 1) << 16) + (mat << 15) + (half << 14) + ldsw];
    GLOAD_LDS16(g + g0, l);
    GLOAD_LDS16(g + g1, l + 1024);
  };

  // fragment reads (swizzled): row*128 + ((ks*32 + hi*16) ^ (f(row)<<4));
  // f(row) = (l5&7)^((l5>>3)&3) for ALL fragments (row strides are mult of 32).
  const int fswz  = ((l5 & 7) ^ (l5 >> 3)) << 4;   // (l5>>3) is 2 bits
  const int a_row = (wr * 128 + l5) * 128;
  const int b_row = 32768 + (wc * 64 + l5) * 128;
  int kof[4];
  #pragma unroll
  for (int ks = 0; ks < 4; ++ks) kof[ks] = (ks * 32 + hi * 16) ^ fswz;

  i32x16 acc[4][2];
  #pragma unroll
  for (int m = 0; m < 4; ++m)
    #pragma unroll
    for (int n = 0; n < 2; ++n)
      #pragma unroll
      for (int r = 0; r < 16; ++r) acc[m][n][r] = 0;

  // prologue: tile 0 (8 loads) then tile 1 (8 loads); wait tile 0 complete.
  stage(0, 0, 0); stage(0, 1, 0); stage(1, 0, 0); stage(1, 1, 0);
  stage(0, 0, 1); stage(0, 1, 1); stage(1, 0, 1); stage(1, 1, 1);
  VMCNT8();
  BAR();

  for (int t = 0; t < NT; ++t) {
    const char* L = &lds[(size_t)(t & 1) << 16];
    i32x4 aF[4][4], bF[2][4];

    // ================= R1: all 24 reads + MFMA m0-1 x n0-1 x ks0-3 ========
    #pragma unroll
    for (int m = 0; m < 4; ++m)
      #pragma unroll
      for (int ks = 0; ks < 4; ++ks)
        aF[m][ks] = *(const i32x4*)(L + a_row + m * 4096 + kof[ks]);
    #pragma unroll
    for (int n = 0; n < 2; ++n)
      #pragma unroll
      for (int ks = 0; ks < 4; ++ks)
        bF[n][ks] = *(const i32x4*)(L + b_row + n * 4096 + kof[ks]);
    PRIO(1);
    #pragma unroll
    for (int m = 0; m < 2; ++m)
      #pragma unroll
      for (int n = 0; n < 2; ++n)
        #pragma unroll
        for (int ks = 0; ks < 4; ++ks)
          acc[m][n] = MFMA32I8(aF[m][ks], bF[n][ks], acc[m][n]);
    PRIO(0);

    // ---- mid: single sync point (buf[t] dead; buf[t+1] resident)
    WAITALL();
    BAR();

    // ================= R2: stage t+2 + MFMA m2-3 x n0-1 x ks0-3 ===========
    if (t + 2 < NT) {
      stage(1, 0, t + 2); stage(1, 1, t + 2);   // B halves
      stage(0, 0, t + 2); stage(0, 1, t + 2);   // A halves
    }
    PRIO(1);
    #pragma unroll
    for (int m = 2; m < 4; ++m)
      #pragma unroll
      for (int n = 0; n < 2; ++n)
        #pragma unroll
        for (int ks = 0; ks < 4; ++ks)
          acc[m][n] = MFMA32I8(aF[m][ks], bF[n][ks], acc[m][n]);
    PRIO(0);
  }

  // epilogue: 32x32 C/D layout col=lane&31, row=(r&3)+8*(r>>2)+4*(lane>>5)
  // [m74/m101-verified]; y = acc * scale[row]
  const int grow0 = bm * BM + wr * 128;
  float* Cp = C + (size_t)grow0 * N_OUT + bn * BN + wc * 64;
  #pragma unroll
  for (int m = 0; m < 4; ++m)
    #pragma unroll
    for (int r = 0; r < 16; ++r) {
      const int rowin = m * 32 + (r & 3) + 8 * (r >> 2) + 4 * hi;
      const float s = scales[grow0 + rowin];
      Cp[(size_t)rowin * N_OUT + l5]      = (float)acc[m][0][r] * s;
      Cp[(size_t)rowin * N_OUT + 32 + l5] = (float)acc[m][1][r] * s;
    }
}

// ---------------- fallback (ws too small): fp32 LDS-tiled, correct but slow --
__global__ __launch_bounds__(256) void fb_gemm(const float* __restrict__ x,
                                               const float* __restrict__ W,
                                               float* __restrict__ y) {
  __shared__ float xs[32][33];
  __shared__ float ws[32][33];
  const int bx = blockIdx.x;
  const int by = blockIdx.y;
  const int tx = threadIdx.x & 31;
  const int ty = threadIdx.x >> 5;
  float acc[4] = {0.f, 0.f, 0.f, 0.f};
  for (int k0 = 0; k0 < K_IN; k0 += 32) {
    #pragma unroll
    for (int i = 0; i < 4; ++i) {
      int r = ty + i * 8;
      xs[r][tx] = x[(size_t)(by * 32 + r) * K_IN + k0 + tx];
      float wv = W[(size_t)(bx * 32 + r) * K_IN + k0 + tx];
      ws[r][tx] = wv > 0.f ? 1.f : (wv < 0.f ? -1.f : 0.f);
    }
    __syncthreads();
    #pragma unroll
    for (int i = 0; i < 4; ++i) {
      int r = ty + i * 8;
      float s = acc[i];
      #pragma unroll
      for (int k = 0; k < 32; ++k) s += xs[r][k] * ws[tx][k];
      acc[i] = s;
    }
    __syncthreads();
  }
  #pragma unroll
  for (int i = 0; i < 4; ++i)
    y[(size_t)(by * 32 + ty + i * 8) * N_OUT + bx * 32 + tx] = acc[i];
}

extern "C" void kernel_launch(void* const* d_in, const int* in_sizes, int n_in,
                              void* d_out, int out_size, void* d_ws, size_t ws_size,
                              hipStream_t stream) {
  const float* x = (const float*)d_in[0];   // [8192, 4096]
  const float* W = (const float*)d_in[1];   // [4096, 4096]
  float* y = (float*)d_out;                 // [8192, 4096]

  const size_t need = (size_t)M_TOK * K_IN + (size_t)N_OUT * K_IN
                    + (size_t)M_TOK * sizeof(float);
  if (ws_size >= need) {
    char*  xq = (char*)d_ws;
    char*  wq = xq + (size_t)M_TOK * K_IN;
    float* sc = (float*)(wq + (size_t)N_OUT * K_IN);
    quant_x_i8<<<M_TOK, 256, 0, stream>>>((const float4*)x, (int4*)xq, sc);
    sgn_w_i8<<<2048, 256, 0, stream>>>((const float4*)W, (int4*)wq,
                                       N_OUT * K_IN / 16);
    bin_gemm_i8<<<(M_TOK / BM) * (N_OUT / BN), 512, 0, stream>>>(xq, wq, sc, y);
  } else {
    dim3 g(N_OUT / 32, M_TOK / 32);
    fb_gemm<<<g, 256, 0, stream>>>(x, W, y);
  }
}